// Round 4
// baseline (138.941 us; speedup 1.0000x reference)
//
#include <hip/hip_runtime.h>

#define THR_F     0.2f
#define TANH_THR  0.19737532f   // tanh(0.2), fp32-rounded

// ---------------------------------------------------------------------------
// helpers
// ---------------------------------------------------------------------------
__device__ __forceinline__ float fast_tanh(float x) {
    x = fminf(10.f, fmaxf(-10.f, x));
    float e = __expf(2.f * x);
    return (e - 1.f) * __builtin_amdgcn_rcpf(e + 1.f);
}

// monotone float <-> uint key for atomicMax on floats
__device__ __forceinline__ unsigned fkey(float f) {
    unsigned u = __float_as_uint(f);
    return (u & 0x80000000u) ? ~u : (u | 0x80000000u);
}
__device__ __forceinline__ float fdecode(unsigned u) {
    return __uint_as_float((u & 0x80000000u) ? (u & 0x7FFFFFFFu) : ~u);
}

// pack two floats into a uint as 2x bf16 (round-to-nearest-even)
__device__ __forceinline__ unsigned pk_bf16(float lo, float hi) {
    unsigned ul = __float_as_uint(lo);
    unsigned uh = __float_as_uint(hi);
    ul += 0x7FFFu + ((ul >> 16) & 1u);
    uh += 0x7FFFu + ((uh >> 16) & 1u);
    return (ul >> 16) | (uh & 0xFFFF0000u);
}
__device__ __forceinline__ float bf_lo(unsigned u) { return __uint_as_float(u << 16); }
__device__ __forceinline__ float bf_hi(unsigned u) { return __uint_as_float(u & 0xFFFF0000u); }

// ---------------------------------------------------------------------------
// Kernel 0: prep. Grid = 480 blocks x 64 threads (one wave each).
//  blocks 0..383   : (b,n)=bid -> base[b*24+n] = dot(nullary[b],K[n,0:128])
//                    + THR - ssq[n]*tanh(THR)
//  blocks 384..479 : pack Wb/Wu (6144 elems, 64/block); blocks 384-386 also
//                    zero max0[128] + ticket (192 u32 total).
// and_kernel layout: (3,8,640) -> ac = a*8+c rows of 640
//   cols 0:128 null | 128:256 u(o0) | 256:384 u(o1) | 384:512 b(o0,j01) | 512:640 b(o1,j10)
// ---------------------------------------------------------------------------
__global__ __launch_bounds__(64) void prep_kernel(
    const float* __restrict__ nullary,   // [16][128]
    const float* __restrict__ andk,      // [24][640]
    float* __restrict__ Wb,              // [128][48] packed binary weights
    float* __restrict__ Wu,              // [128][48] packed unary weights
    float* __restrict__ base,            // [16][24]
    unsigned* __restrict__ max0)         // [16][8] + ticket at [128]
{
    const int bid = blockIdx.x;
    const int t   = threadIdx.x;
    if (bid < 384) {
        const int b = bid / 24, n = bid % 24;
        const float* w  = andk + n * 640;
        const float* nu = nullary + b * 128;
        float s = 0.f;
        #pragma unroll
        for (int i = 0; i < 10; ++i) { float v = w[t + i * 64]; s = fmaf(v, v, s); }
        float d = fmaf(nu[t], w[t], 0.f);
        d = fmaf(nu[t + 64], w[t + 64], d);
        #pragma unroll
        for (int m = 32; m; m >>= 1) {
            s += __shfl_xor(s, m, 64);
            d += __shfl_xor(d, m, 64);
        }
        if (t == 0) base[bid] = d + THR_F - s * TANH_THR;
    } else {
        const int i = (bid - 384) * 64 + t;   // 0..6143
        const int k = i / 48, n = i % 48;
        const int ac   = (n < 24) ? n : n - 24;
        const int colb = (n < 24) ? 384 : 512;
        const int colu = (n < 24) ? 128 : 256;
        Wb[i] = andk[ac * 640 + colb + k];
        Wu[i] = andk[ac * 640 + colu + k];
        if (bid < 387) {
            int idx = (bid - 384) * 64 + t;
            if (idx < 192) max0[idx] = 0u;   // 128 max slots + ticket + pad
        }
    }
}

// ---------------------------------------------------------------------------
// Kernel 1: projections. Grid = 1024 blocks x 256 threads (4 waves).
//  blocks 0..1007: binary rows (64 rows/block); 1008..1023: unary rows.
//  Wave w computes a 12-channel slice; lane = row; weights via s_load.
//  P0 / P1T are stored as PACKED BF16 (write-once/read-once intermediates;
//  bf16 error ~2e-4 -> ~1e-5 in outputs, threshold 4.45e-3).
//  P1 is transposed: P1T[b][j10][o1][24] so combine's o1-varying read is
//  contiguous across lanes.
// ---------------------------------------------------------------------------
__global__ __launch_bounds__(256) void proj_kernel(
    const float* __restrict__ unary,     // [1024][128]
    const float* __restrict__ binary,    // [64512][128]
    const float* __restrict__ Wb,        // [128][48]
    const float* __restrict__ Wu,        // [128][48]
    unsigned* __restrict__ P0,           // [64512][12] packed bf16 pairs
    unsigned* __restrict__ P1T,          // [16][63][64][12] packed
    float* __restrict__ U0, float* __restrict__ U1)   // [1024][24] fp32
{
    const int bid  = blockIdx.x;
    const int wave = __builtin_amdgcn_readfirstlane((int)(threadIdx.x >> 6)); // 0..3
    const int lane = threadIdx.x & 63;
    const bool is_bin = (bid < 1008);

    const int row = is_bin ? (bid * 64 + lane) : ((bid - 1008) * 64 + lane);
    const float* __restrict__ W   = (is_bin ? Wb : Wu) + wave * 12;
    const float* __restrict__ src = (is_bin ? binary : unary) + (size_t)row * 128;

    float acc[12];
    #pragma unroll
    for (int n = 0; n < 12; ++n) acc[n] = 0.f;

    const float4* rp = (const float4*)src;
    #pragma unroll 8
    for (int k4 = 0; k4 < 32; ++k4) {
        float4 a = rp[k4];
        const float* wk = W + k4 * 4 * 48;
        #pragma unroll
        for (int q = 0; q < 4; ++q) {
            float av = (q == 0) ? a.x : (q == 1) ? a.y : (q == 2) ? a.z : a.w;
            const float* w = wk + q * 48;
            #pragma unroll
            for (int n = 0; n < 12; ++n) acc[n] = fmaf(av, w[n], acc[n]);
        }
    }

    if (is_bin) {
        unsigned* dstp;
        if (wave < 2) {
            dstp = P0 + (size_t)row * 12 + (wave & 1) * 6;
        } else {
            const int b   = row / 4032;          // 64*63
            const int rem = row - b * 4032;
            const int o   = rem / 63;
            const int j   = rem - o * 63;
            dstp = P1T + ((size_t)(b * 63 + j) * 64 + o) * 12 + (wave & 1) * 6;
        }
        unsigned pk[6];
        #pragma unroll
        for (int i = 0; i < 6; ++i) pk[i] = pk_bf16(acc[2*i], acc[2*i+1]);
        uint2* d2 = (uint2*)dstp;
        d2[0] = make_uint2(pk[0], pk[1]);
        d2[1] = make_uint2(pk[2], pk[3]);
        d2[2] = make_uint2(pk[4], pk[5]);
    } else {
        float* dst = ((wave < 2) ? U0 : U1) + (size_t)row * 24 + (wave & 1) * 12;
        float4* d4 = (float4*)dst;
        #pragma unroll
        for (int i = 0; i < 3; ++i)
            d4[i] = make_float4(acc[i*4+0], acc[i*4+1], acc[i*4+2], acc[i*4+3]);
    }
}

// ---------------------------------------------------------------------------
// Kernel 2: combine + tanh + reductions + OR stage + fused finalize.
// Grid = 1024 blocks (b,o0) x 192 threads (3 waves). Wave a handles stage a:
//   a=0: wave-max over perms -> atomicMax; last block (atomic ticket) also
//        reads max0 back via coherent-point atomics and writes out[0..15]
//   a=1: wave-max over o1 -> OR dot -> out1[b,o0]
//   a=2: direct OR dot -> out2[b,o0,j01] per lane
// lane t -> o1 = t + (t>=o0), j01 = t, jrow = o0 - (t<o0).
// ---------------------------------------------------------------------------
__global__ __launch_bounds__(192) void combine_kernel(
    const float* __restrict__ base,   // [16][24]
    const float* __restrict__ U0, const float* __restrict__ U1,  // [1024][24]
    const unsigned* __restrict__ P0,  // [64512][12] packed bf16
    const unsigned* __restrict__ P1T, // [16][63][64][12] packed bf16
    const float* __restrict__ ork,    // [3][8]
    unsigned* __restrict__ max0,      // [16][8], ticket at [128]
    float* __restrict__ out)          // [16] + [1024] + [64512]
{
    const int bid = blockIdx.x;
    const int b   = bid >> 6;
    const int o0  = bid & 63;
    const int a   = __builtin_amdgcn_readfirstlane((int)(threadIdx.x >> 6)); // 0..2
    const int t   = threadIdx.x & 63;
    const bool act = (t < 63);

    const int o1   = min(t + (t >= o0 ? 1 : 0), 63);
    const int jrow = min((t < o0) ? (o0 - 1) : o0, 62);   // == j10, clamped lane 63
    const int j01  = min(t, 62);
    const int ch   = a * 8;

    const float* pb  = base + b * 24 + ch;                                  // uniform
    const float* pa0 = U0 + (size_t)(b * 64 + o0) * 24 + ch;                // uniform
    const float4* A1 = (const float4*)(U1 + (size_t)(b * 64 + o1) * 24 + ch);
    const uint4*  Q0 = (const uint4*)(P0 + (size_t)((b * 64 + o0) * 63 + j01) * 12 + a * 4);
    const uint4*  Q1 = (const uint4*)(P1T + ((size_t)(b * 63 + jrow) * 64 + o1) * 12 + a * 4);

    uint4 q0 = *Q0, q1 = *Q1;
    float4 a1l = A1[0], a1h = A1[1];

    float th[8];
    th[0] = pb[0] + pa0[0] + a1l.x + bf_lo(q0.x) + bf_lo(q1.x);
    th[1] = pb[1] + pa0[1] + a1l.y + bf_hi(q0.x) + bf_hi(q1.x);
    th[2] = pb[2] + pa0[2] + a1l.z + bf_lo(q0.y) + bf_lo(q1.y);
    th[3] = pb[3] + pa0[3] + a1l.w + bf_hi(q0.y) + bf_hi(q1.y);
    th[4] = pb[4] + pa0[4] + a1h.x + bf_lo(q0.z) + bf_lo(q1.z);
    th[5] = pb[5] + pa0[5] + a1h.y + bf_hi(q0.z) + bf_hi(q1.z);
    th[6] = pb[6] + pa0[6] + a1h.z + bf_lo(q0.w) + bf_lo(q1.w);
    th[7] = pb[7] + pa0[7] + a1h.w + bf_hi(q0.w) + bf_hi(q1.w);
    #pragma unroll
    for (int n = 0; n < 8; ++n) th[n] = fast_tanh(th[n]);

    if (a == 2) {
        if (act) {
            float v = 0.f, b2 = 0.f;
            #pragma unroll
            for (int c = 0; c < 8; ++c) {
                float k = ork[16 + c];
                v  = fmaf(th[c], k, v);
                b2 = fmaf(k, k, b2);
            }
            out[16 + 1024 + ((b * 64 + o0) * 63 + t)] = v + b2 * TANH_THR - THR_F;
        }
        return;
    }

    // mask inactive lane for the max reductions
    if (!act) {
        #pragma unroll
        for (int n = 0; n < 8; ++n) th[n] = -2.0f;
    }
    #pragma unroll
    for (int n = 0; n < 8; ++n) {
        float v = th[n];
        #pragma unroll
        for (int m = 32; m; m >>= 1) v = fmaxf(v, __shfl_xor(v, m, 64));
        th[n] = v;
    }

    if (a == 1) {
        if (t == 0) {
            float v1 = 0.f, b1 = 0.f;
            #pragma unroll
            for (int c = 0; c < 8; ++c) {
                float k = ork[8 + c];
                v1 = fmaf(th[c], k, v1);
                b1 = fmaf(k, k, b1);
            }
            out[16 + b * 64 + o0] = v1 + b1 * TANH_THR - THR_F;
        }
        return;
    }

    // a == 0: global max via atomicMax, then last-block finalize
    unsigned rank = 0u;
    if (t == 0) {
        #pragma unroll
        for (int c = 0; c < 8; ++c)
            atomicMax(&max0[b * 8 + c], fkey(th[c]));
        __threadfence();                       // drain the umax ops (vmcnt)
        rank = atomicAdd(&max0[128], 1u) + 1u; // ticket
    }
    rank = __shfl(rank, 0, 64);
    if (rank == 1024u && t < 16) {
        float v = 0.f, bb = 0.f;
        #pragma unroll
        for (int c = 0; c < 8; ++c) {
            float m = fdecode(atomicAdd(&max0[t * 8 + c], 0u)); // coherent read
            float k = ork[c];
            v  = fmaf(m, k, v);
            bb = fmaf(k, k, bb);
        }
        out[t] = v + bb * TANH_THR - THR_F;
    }
}

// ---------------------------------------------------------------------------
// launcher
// ---------------------------------------------------------------------------
extern "C" void kernel_launch(void* const* d_in, const int* in_sizes, int n_in,
                              void* d_out, int out_size, void* d_ws, size_t ws_size,
                              hipStream_t stream)
{
    const float* nullary = (const float*)d_in[0];   // (16,128)
    const float* unary   = (const float*)d_in[1];   // (16,64,128)
    const float* binary  = (const float*)d_in[2];   // (16,64,63,128)
    const float* andk    = (const float*)d_in[3];   // (3,8,640)
    const float* ork     = (const float*)d_in[4];   // (3,8)
    float* out = (float*)d_out;

    float* ws = (float*)d_ws;
    float*    base = ws;                           // 384
    float*    U0   = ws + 384;                     // 24576
    float*    U1   = ws + 24960;                   // 24576
    float*    Wb   = ws + 49536;                   // 6144
    float*    Wu   = ws + 55680;                   // 6144
    unsigned* P0   = (unsigned*)(ws + 61824);      // 774144 u32 (bf16 pairs)
    unsigned* P1T  = (unsigned*)(ws + 835968);     // 774144 u32
    unsigned* max0 = (unsigned*)(ws + 1610112);    // 128 max slots + ticket + pad

    prep_kernel<<<480, 64, 0, stream>>>(nullary, andk, Wb, Wu, base, max0);
    proj_kernel<<<1024, 256, 0, stream>>>(unary, binary, Wb, Wu, P0, P1T, U0, U1);
    combine_kernel<<<1024, 192, 0, stream>>>(base, U0, U1, P0, P1T, ork, max0, out);
}

// Round 5
// 130.525 us; speedup vs baseline: 1.0645x; 1.0645x over previous
//
#include <hip/hip_runtime.h>

#define THR_F     0.2f
#define TANH_THR  0.19737532f   // tanh(0.2), fp32-rounded

// ---------------------------------------------------------------------------
// helpers
// ---------------------------------------------------------------------------
__device__ __forceinline__ float fast_tanh(float x) {
    x = fminf(10.f, fmaxf(-10.f, x));
    float e = __expf(2.f * x);
    return (e - 1.f) * __builtin_amdgcn_rcpf(e + 1.f);
}

// monotone float <-> uint key for atomicMax on floats
__device__ __forceinline__ unsigned fkey(float f) {
    unsigned u = __float_as_uint(f);
    return (u & 0x80000000u) ? ~u : (u | 0x80000000u);
}
__device__ __forceinline__ float fdecode(unsigned u) {
    return __uint_as_float((u & 0x80000000u) ? (u & 0x7FFFFFFFu) : ~u);
}

// pack two floats into a uint as 2x bf16 (round-to-nearest-even)
__device__ __forceinline__ unsigned pk_bf16(float lo, float hi) {
    unsigned ul = __float_as_uint(lo);
    unsigned uh = __float_as_uint(hi);
    ul += 0x7FFFu + ((ul >> 16) & 1u);
    uh += 0x7FFFu + ((uh >> 16) & 1u);
    return (ul >> 16) | (uh & 0xFFFF0000u);
}
__device__ __forceinline__ float bf_lo(unsigned u) { return __uint_as_float(u << 16); }
__device__ __forceinline__ float bf_hi(unsigned u) { return __uint_as_float(u & 0xFFFF0000u); }

// ---------------------------------------------------------------------------
// Kernel 0: prep. Grid = 480 blocks x 64 threads (one wave each).
//  blocks 0..383   : (b,n)=bid -> base[b*24+n] = dot(nullary[b],K[n,0:128])
//                    + THR - ssq[n]*tanh(THR)
//  blocks 384..479 : pack Wb/Wu (6144 elems, 64/block); blocks 384-386 also
//                    zero max0[128] (+pad).
// and_kernel layout: (3,8,640) -> ac = a*8+c rows of 640
//   cols 0:128 null | 128:256 u(o0) | 256:384 u(o1) | 384:512 b(o0,j01) | 512:640 b(o1,j10)
// ---------------------------------------------------------------------------
__global__ __launch_bounds__(64) void prep_kernel(
    const float* __restrict__ nullary,   // [16][128]
    const float* __restrict__ andk,      // [24][640]
    float* __restrict__ Wb,              // [128][48] packed binary weights
    float* __restrict__ Wu,              // [128][48] packed unary weights
    float* __restrict__ base,            // [16][24]
    unsigned* __restrict__ max0)         // [16][8] (+pad)
{
    const int bid = blockIdx.x;
    const int t   = threadIdx.x;
    if (bid < 384) {
        const int b = bid / 24, n = bid % 24;
        const float* w  = andk + n * 640;
        const float* nu = nullary + b * 128;
        float s = 0.f;
        #pragma unroll
        for (int i = 0; i < 10; ++i) { float v = w[t + i * 64]; s = fmaf(v, v, s); }
        float d = fmaf(nu[t], w[t], 0.f);
        d = fmaf(nu[t + 64], w[t + 64], d);
        #pragma unroll
        for (int m = 32; m; m >>= 1) {
            s += __shfl_xor(s, m, 64);
            d += __shfl_xor(d, m, 64);
        }
        if (t == 0) base[bid] = d + THR_F - s * TANH_THR;
    } else {
        const int i = (bid - 384) * 64 + t;   // 0..6143
        const int k = i / 48, n = i % 48;
        const int ac   = (n < 24) ? n : n - 24;
        const int colb = (n < 24) ? 384 : 512;
        const int colu = (n < 24) ? 128 : 256;
        Wb[i] = andk[ac * 640 + colb + k];
        Wu[i] = andk[ac * 640 + colu + k];
        if (bid < 387) {
            int idx = (bid - 384) * 64 + t;
            if (idx < 192) max0[idx] = 0u;   // 128 max slots + pad
        }
    }
}

// ---------------------------------------------------------------------------
// Kernel 1: projections. Grid = 1024 blocks x 256 threads (4 waves).
//  blocks 0..1007: binary rows (64 rows/block); 1008..1023: unary rows.
//  Wave w computes a 12-channel slice; lane = row; weights via s_load.
//  P0 / P1T stored as PACKED BF16 (write-once/read-once intermediates;
//  bf16 error ~2e-4 -> ~1e-3 in outputs, threshold 4.45e-3).
//  P1 is transposed: P1T[b][j10][o1][24] so combine's o1-varying read is
//  contiguous across lanes.
// ---------------------------------------------------------------------------
__global__ __launch_bounds__(256) void proj_kernel(
    const float* __restrict__ unary,     // [1024][128]
    const float* __restrict__ binary,    // [64512][128]
    const float* __restrict__ Wb,        // [128][48]
    const float* __restrict__ Wu,        // [128][48]
    unsigned* __restrict__ P0,           // [64512][12] packed bf16 pairs
    unsigned* __restrict__ P1T,          // [16][63][64][12] packed
    float* __restrict__ U0, float* __restrict__ U1)   // [1024][24] fp32
{
    const int bid  = blockIdx.x;
    const int wave = __builtin_amdgcn_readfirstlane((int)(threadIdx.x >> 6)); // 0..3
    const int lane = threadIdx.x & 63;
    const bool is_bin = (bid < 1008);

    const int row = is_bin ? (bid * 64 + lane) : ((bid - 1008) * 64 + lane);
    const float* __restrict__ W   = (is_bin ? Wb : Wu) + wave * 12;
    const float* __restrict__ src = (is_bin ? binary : unary) + (size_t)row * 128;

    float acc[12];
    #pragma unroll
    for (int n = 0; n < 12; ++n) acc[n] = 0.f;

    const float4* rp = (const float4*)src;
    #pragma unroll 8
    for (int k4 = 0; k4 < 32; ++k4) {
        float4 a = rp[k4];
        const float* wk = W + k4 * 4 * 48;
        #pragma unroll
        for (int q = 0; q < 4; ++q) {
            float av = (q == 0) ? a.x : (q == 1) ? a.y : (q == 2) ? a.z : a.w;
            const float* w = wk + q * 48;
            #pragma unroll
            for (int n = 0; n < 12; ++n) acc[n] = fmaf(av, w[n], acc[n]);
        }
    }

    if (is_bin) {
        unsigned* dstp;
        if (wave < 2) {
            dstp = P0 + (size_t)row * 12 + (wave & 1) * 6;
        } else {
            const int b   = row / 4032;          // 64*63
            const int rem = row - b * 4032;
            const int o   = rem / 63;
            const int j   = rem - o * 63;
            dstp = P1T + ((size_t)(b * 63 + j) * 64 + o) * 12 + (wave & 1) * 6;
        }
        unsigned pk[6];
        #pragma unroll
        for (int i = 0; i < 6; ++i) pk[i] = pk_bf16(acc[2*i], acc[2*i+1]);
        uint2* d2 = (uint2*)dstp;
        d2[0] = make_uint2(pk[0], pk[1]);
        d2[1] = make_uint2(pk[2], pk[3]);
        d2[2] = make_uint2(pk[4], pk[5]);
    } else {
        float* dst = ((wave < 2) ? U0 : U1) + (size_t)row * 24 + (wave & 1) * 12;
        float4* d4 = (float4*)dst;
        #pragma unroll
        for (int i = 0; i < 3; ++i)
            d4[i] = make_float4(acc[i*4+0], acc[i*4+1], acc[i*4+2], acc[i*4+3]);
    }
}

// ---------------------------------------------------------------------------
// Kernel 2: combine + tanh + reductions + OR stage.
// Grid = 1024 blocks (b,o0) x 192 threads (3 waves). Wave a handles stage a:
//   a=0: wave-max over perms -> atomicMax (device-scope; NO fence/ticket —
//        the R4 fused-finalize's per-block threadfence cost ~+15 us)
//   a=1: wave-max over o1 -> OR dot -> out1[b,o0]
//   a=2: direct OR dot -> out2[b,o0,j01] per lane
// lane t -> o1 = t + (t>=o0), j01 = t, jrow = o0 - (t<o0).
// ---------------------------------------------------------------------------
__global__ __launch_bounds__(192) void combine_kernel(
    const float* __restrict__ base,   // [16][24]
    const float* __restrict__ U0, const float* __restrict__ U1,  // [1024][24]
    const unsigned* __restrict__ P0,  // [64512][12] packed bf16
    const unsigned* __restrict__ P1T, // [16][63][64][12] packed bf16
    const float* __restrict__ ork,    // [3][8]
    unsigned* __restrict__ max0,      // [16][8]
    float* __restrict__ out)          // [16] + [1024] + [64512]
{
    const int bid = blockIdx.x;
    const int b   = bid >> 6;
    const int o0  = bid & 63;
    const int a   = __builtin_amdgcn_readfirstlane((int)(threadIdx.x >> 6)); // 0..2
    const int t   = threadIdx.x & 63;
    const bool act = (t < 63);

    const int o1   = min(t + (t >= o0 ? 1 : 0), 63);
    const int jrow = min((t < o0) ? (o0 - 1) : o0, 62);   // == j10, clamped lane 63
    const int j01  = min(t, 62);
    const int ch   = a * 8;

    const float* pb  = base + b * 24 + ch;                                  // uniform
    const float* pa0 = U0 + (size_t)(b * 64 + o0) * 24 + ch;                // uniform
    const float4* A1 = (const float4*)(U1 + (size_t)(b * 64 + o1) * 24 + ch);
    const uint4*  Q0 = (const uint4*)(P0 + (size_t)((b * 64 + o0) * 63 + j01) * 12 + a * 4);
    const uint4*  Q1 = (const uint4*)(P1T + ((size_t)(b * 63 + jrow) * 64 + o1) * 12 + a * 4);

    uint4 q0 = *Q0, q1 = *Q1;
    float4 a1l = A1[0], a1h = A1[1];

    float th[8];
    th[0] = pb[0] + pa0[0] + a1l.x + bf_lo(q0.x) + bf_lo(q1.x);
    th[1] = pb[1] + pa0[1] + a1l.y + bf_hi(q0.x) + bf_hi(q1.x);
    th[2] = pb[2] + pa0[2] + a1l.z + bf_lo(q0.y) + bf_lo(q1.y);
    th[3] = pb[3] + pa0[3] + a1l.w + bf_hi(q0.y) + bf_hi(q1.y);
    th[4] = pb[4] + pa0[4] + a1h.x + bf_lo(q0.z) + bf_lo(q1.z);
    th[5] = pb[5] + pa0[5] + a1h.y + bf_hi(q0.z) + bf_hi(q1.z);
    th[6] = pb[6] + pa0[6] + a1h.z + bf_lo(q0.w) + bf_lo(q1.w);
    th[7] = pb[7] + pa0[7] + a1h.w + bf_hi(q0.w) + bf_hi(q1.w);
    #pragma unroll
    for (int n = 0; n < 8; ++n) th[n] = fast_tanh(th[n]);

    if (a == 2) {
        if (act) {
            float v = 0.f, b2 = 0.f;
            #pragma unroll
            for (int c = 0; c < 8; ++c) {
                float k = ork[16 + c];
                v  = fmaf(th[c], k, v);
                b2 = fmaf(k, k, b2);
            }
            out[16 + 1024 + ((b * 64 + o0) * 63 + t)] = v + b2 * TANH_THR - THR_F;
        }
        return;
    }

    // mask inactive lane for the max reductions
    if (!act) {
        #pragma unroll
        for (int n = 0; n < 8; ++n) th[n] = -2.0f;
    }
    #pragma unroll
    for (int n = 0; n < 8; ++n) {
        float v = th[n];
        #pragma unroll
        for (int m = 32; m; m >>= 1) v = fmaxf(v, __shfl_xor(v, m, 64));
        th[n] = v;
    }

    if (t == 0) {
        if (a == 1) {
            float v1 = 0.f, b1 = 0.f;
            #pragma unroll
            for (int c = 0; c < 8; ++c) {
                float k = ork[8 + c];
                v1 = fmaf(th[c], k, v1);
                b1 = fmaf(k, k, b1);
            }
            out[16 + b * 64 + o0] = v1 + b1 * TANH_THR - THR_F;
        } else {
            #pragma unroll
            for (int c = 0; c < 8; ++c)
                atomicMax(&max0[b * 8 + c], fkey(th[c]));
        }
    }
}

// ---------------------------------------------------------------------------
// Kernel 3: finalize out0 from the atomicMax workspace
// ---------------------------------------------------------------------------
__global__ __launch_bounds__(64) void finalize_kernel(
    const unsigned* __restrict__ max0,
    const float* __restrict__ ork,
    float* __restrict__ out)
{
    int b = threadIdx.x;
    if (b >= 16) return;
    float v = 0.f, bb = 0.f;
    #pragma unroll
    for (int c = 0; c < 8; ++c) {
        float m = fdecode(max0[b * 8 + c]);
        float k = ork[c];
        v  = fmaf(m, k, v);
        bb = fmaf(k, k, bb);
    }
    out[b] = v + bb * TANH_THR - THR_F;
}

// ---------------------------------------------------------------------------
// launcher
// ---------------------------------------------------------------------------
extern "C" void kernel_launch(void* const* d_in, const int* in_sizes, int n_in,
                              void* d_out, int out_size, void* d_ws, size_t ws_size,
                              hipStream_t stream)
{
    const float* nullary = (const float*)d_in[0];   // (16,128)
    const float* unary   = (const float*)d_in[1];   // (16,64,128)
    const float* binary  = (const float*)d_in[2];   // (16,64,63,128)
    const float* andk    = (const float*)d_in[3];   // (3,8,640)
    const float* ork     = (const float*)d_in[4];   // (3,8)
    float* out = (float*)d_out;

    float* ws = (float*)d_ws;
    float*    base = ws;                           // 384
    float*    U0   = ws + 384;                     // 24576
    float*    U1   = ws + 24960;                   // 24576
    float*    Wb   = ws + 49536;                   // 6144
    float*    Wu   = ws + 55680;                   // 6144
    unsigned* P0   = (unsigned*)(ws + 61824);      // 774144 u32 (bf16 pairs)
    unsigned* P1T  = (unsigned*)(ws + 835968);     // 774144 u32
    unsigned* max0 = (unsigned*)(ws + 1610112);    // 128 max slots + pad

    prep_kernel<<<480, 64, 0, stream>>>(nullary, andk, Wb, Wu, base, max0);
    proj_kernel<<<1024, 256, 0, stream>>>(unary, binary, Wb, Wu, P0, P1T, U0, U1);
    combine_kernel<<<1024, 192, 0, stream>>>(base, U0, U1, P0, P1T, ork, max0, out);
    finalize_kernel<<<1, 64, 0, stream>>>(max0, ork, out);
}